// Round 1
// baseline (674.338 us; speedup 1.0000x reference)
//
#include <hip/hip_runtime.h>

// Problem constants: B=64, N=64, P=512, M=512.
#define B_ 64
#define N_ 64
#define P_ 512
#define M_ 512

#define PPB  8                      // pairs per block
#define NBLK (B_ * P_ / PPB)        // 4096 blocks (divisible by 8 for XCD swizzle)
#define NXCD 8

// Raw clang vector type: __builtin_nontemporal_store needs a real vector type,
// not HIP's float4 struct.
typedef float f4 __attribute__((ext_vector_type(4)));

__global__ __launch_bounds__(256) void ooi_gather_kernel(
    const float* __restrict__ obj_ft,        // [B, N, M]
    const float* __restrict__ node_emb,      // [B, N, M]
    const float* __restrict__ edge_emb,      // [B, N, N, M]
    const int*   __restrict__ pairs,         // [B, P, 2] (int32)
    float* __restrict__ out)                 // [B, P, 3M]
{
    // Bijective XCD-aware swizzle: HW round-robins blockIdx.x across the 8
    // XCDs, so remap launched index L -> virtual block vb such that each XCD
    // processes a CONTIGUOUS range of pairs (contiguous batches). Per-XCD L2
    // then holds that batch's node/obj (256 KB) + hot edge rows.
    const int L  = blockIdx.x;
    const int vb = (L & (NXCD - 1)) * (NBLK / NXCD) + (L >> 3);

    const int half = threadIdx.x >> 7;    // 0/1: which pair of this iteration
    const int t    = threadIdx.x & 127;   // float4 slot within an M-chunk

    const int pair_base = vb * PPB;       // 8 consecutive pairs, same batch
    const int b         = pair_base >> 9; // / P_   (PPB divides P_, no straddle)

    // Preload ALL pair indices first: pulls the dependent scalar-ish loads out
    // of the loop so every iteration's vector loads can be issued back-to-back.
    const int2* pairs2 = (const int2*)pairs;
    int2 pr[PPB / 2];
    #pragma unroll
    for (int k = 0; k < PPB / 2; ++k)
        pr[k] = pairs2[pair_base + 2 * k + half];

    const float* nb = node_emb + (size_t)b * (N_ * M_);
    const float* ob = obj_ft   + (size_t)b * (N_ * M_);
    const float* eb = edge_emb + (size_t)b * ((size_t)N_ * N_ * M_);

    #pragma unroll
    for (int k = 0; k < PPB / 2; ++k) {
        const int p  = pair_base + 2 * k + half;
        const int i0 = pr[k].x;
        const int i1 = pr[k].y;

        const f4* n0  = (const f4*)(nb + (size_t)i0 * M_);
        const f4* n1  = (const f4*)(nb + (size_t)i1 * M_);
        const f4* o0  = (const f4*)(ob + (size_t)i0 * M_);
        const f4* o1  = (const f4*)(ob + (size_t)i1 * M_);
        const f4* e01 = (const f4*)(eb + ((size_t)(i0 * N_ + i1)) * M_);
        const f4* e10 = (const f4*)(eb + ((size_t)(i1 * N_ + i0)) * M_);

        f4* outp = (f4*)(out + (size_t)p * (3 * M_));

        // All 6 loads issued before any store (restrict lets the compiler
        // hoist; distinct named values keep them in registers).
        f4 a0 = n0[t],  c0 = o0[t];
        f4 a1 = n1[t],  c1 = o1[t];
        f4 a2 = e01[t], c2 = e10[t];

        // out is written once and never read: nontemporal stores keep the
        // 201 MB output stream from evicting the gather rows out of L2.
        __builtin_nontemporal_store(0.5f * (a0 + c0), outp + t);
        __builtin_nontemporal_store(0.5f * (a1 + c1), outp + 128 + t);
        __builtin_nontemporal_store(0.5f * (a2 + c2), outp + 256 + t);
    }
}

extern "C" void kernel_launch(void* const* d_in, const int* in_sizes, int n_in,
                              void* d_out, int out_size, void* d_ws, size_t ws_size,
                              hipStream_t stream) {
    const float* obj_ft   = (const float*)d_in[0];
    const float* node_emb = (const float*)d_in[1];
    const float* edge_emb = (const float*)d_in[2];
    const int*   pairs    = (const int*)d_in[3];
    float* out = (float*)d_out;

    dim3 grid(NBLK);    // 4096 blocks
    dim3 block(256);
    ooi_gather_kernel<<<grid, block, 0, stream>>>(obj_ft, node_emb, edge_emb,
                                                  pairs, out);
}

// Round 2
// 666.986 us; speedup vs baseline: 1.0110x; 1.0110x over previous
//
#include <hip/hip_runtime.h>

// Problem constants: B=64, N=64, P=512, M=512.
#define B_ 64
#define N_ 64
#define P_ 512
#define M_ 512

// Raw clang vector type (works with __builtin_nontemporal_*).
typedef float f4 __attribute__((ext_vector_type(4)));

#define S_BYTES ((size_t)B_ * N_ * M_ * sizeof(float))   // 8 MiB

// ---------------------------------------------------------------------------
// Kernel A: s[b][i][:] = 0.5*(node_emb[b][i][:] + obj_ft[b][i][:])
// 4096 distinct (b,i) rows; 8 MiB. Normal stores so s allocates in L2/L3 —
// kernel B re-reads each row ~16x.
// ---------------------------------------------------------------------------
__global__ __launch_bounds__(256) void precompute_s_kernel(
    const float* __restrict__ obj_ft,
    const float* __restrict__ node_emb,
    float* __restrict__ s)
{
    const int idx = blockIdx.x * 256 + threadIdx.x;  // f4 index, B*N*M/4 total
    const f4* n = (const f4*)node_emb;
    const f4* o = (const f4*)obj_ft;
    ((f4*)s)[idx] = 0.5f * (n[idx] + o[idx]);
}

// ---------------------------------------------------------------------------
// Kernel B: one block per (b,p) pair, 384 threads (6 waves), wave-uniform
// branch. Chunks 0/1 are pure copies from the precomputed s (L2-hot, 8 MiB);
// chunk 2 averages the two directed edge rows with nontemporal loads (reuse
// ~1.13x — keep the 116 MB edge stream from evicting s out of L2).
// All output stores nontemporal (201 MB written once, never read).
// ---------------------------------------------------------------------------
__global__ __launch_bounds__(384) void gather_pairs_kernel(
    const float* __restrict__ s,         // [B, N, M] precomputed
    const float* __restrict__ edge_emb,  // [B, N, N, M]
    const int*   __restrict__ pairs,     // [B, P, 2] (int32)
    float* __restrict__ out)             // [B, P, 3M]
{
    const int bp  = blockIdx.x;          // [0, B*P)
    const int b   = bp >> 9;             // / P_
    const int tid = threadIdx.x;

    // Wave-uniform broadcast loads of the pair indices.
    const int i0 = pairs[2 * bp + 0];
    const int i1 = pairs[2 * bp + 1];

    f4* outp = (f4*)(out + (size_t)bp * (3 * M_));

    if (tid < 256) {
        // waves 0-3: copy s[b][i0] then s[b][i1] into chunks 0/1.
        const int which = tid >> 7;          // 0 -> i0 chunk, 1 -> i1 chunk
        const int t     = tid & 127;         // float4 slot in the M-chunk
        const int idx   = which ? i1 : i0;
        const f4* srow  = (const f4*)(s + (size_t)(b * N_ + idx) * M_);
        __builtin_nontemporal_store(srow[t], outp + (which << 7) + t);
    } else {
        // waves 4-5: chunk 2 = 0.5*(edge[i0][i1] + edge[i1][i0]).
        const int t = tid - 256;
        const size_t bn0 = (size_t)(b * N_ + i0);
        const size_t bn1 = (size_t)(b * N_ + i1);
        const f4* e01 = (const f4*)(edge_emb + (bn0 * N_ + i1) * (size_t)M_);
        const f4* e10 = (const f4*)(edge_emb + (bn1 * N_ + i0) * (size_t)M_);
        f4 a = __builtin_nontemporal_load(e01 + t);
        f4 c = __builtin_nontemporal_load(e10 + t);
        __builtin_nontemporal_store(0.5f * (a + c), outp + 256 + t);
    }
}

// ---------------------------------------------------------------------------
// Fallback (ws too small): fused single kernel, round-0 structure + NT stores.
// ---------------------------------------------------------------------------
__global__ __launch_bounds__(128) void gather_fused_kernel(
    const float* __restrict__ obj_ft,
    const float* __restrict__ node_emb,
    const float* __restrict__ edge_emb,
    const int*   __restrict__ pairs,
    float* __restrict__ out)
{
    const int bp = blockIdx.x;
    const int b  = bp >> 9;
    const int t  = threadIdx.x;

    const int i0 = pairs[2 * bp + 0];
    const int i1 = pairs[2 * bp + 1];

    const size_t bn0 = (size_t)(b * N_ + i0);
    const size_t bn1 = (size_t)(b * N_ + i1);

    const f4* n0  = (const f4*)(node_emb + bn0 * M_);
    const f4* n1  = (const f4*)(node_emb + bn1 * M_);
    const f4* o0  = (const f4*)(obj_ft   + bn0 * M_);
    const f4* o1  = (const f4*)(obj_ft   + bn1 * M_);
    const f4* e01 = (const f4*)(edge_emb + (bn0 * N_ + i1) * (size_t)M_);
    const f4* e10 = (const f4*)(edge_emb + (bn1 * N_ + i0) * (size_t)M_);

    f4* outp = (f4*)(out + (size_t)bp * (3 * M_));

    __builtin_nontemporal_store(0.5f * (n0[t] + o0[t]), outp + t);
    __builtin_nontemporal_store(0.5f * (n1[t] + o1[t]), outp + 128 + t);
    __builtin_nontemporal_store(0.5f * (e01[t] + e10[t]), outp + 256 + t);
}

extern "C" void kernel_launch(void* const* d_in, const int* in_sizes, int n_in,
                              void* d_out, int out_size, void* d_ws, size_t ws_size,
                              hipStream_t stream) {
    const float* obj_ft   = (const float*)d_in[0];
    const float* node_emb = (const float*)d_in[1];
    const float* edge_emb = (const float*)d_in[2];
    const int*   pairs    = (const int*)d_in[3];
    float* out = (float*)d_out;

    if (d_ws != nullptr && ws_size >= S_BYTES) {
        float* s = (float*)d_ws;
        // A: 524288 f4 elements / 256 = 2048 blocks.
        precompute_s_kernel<<<dim3(B_ * N_ * M_ / 4 / 256), dim3(256), 0, stream>>>(
            obj_ft, node_emb, s);
        // B: one block per pair.
        gather_pairs_kernel<<<dim3(B_ * P_), dim3(384), 0, stream>>>(
            s, edge_emb, pairs, out);
    } else {
        gather_fused_kernel<<<dim3(B_ * P_), dim3(128), 0, stream>>>(
            obj_ft, node_emb, edge_emb, pairs, out);
    }
}